// Round 1
// baseline (215.144 us; speedup 1.0000x reference)
//
#include <hip/hip_runtime.h>
#include <stdint.h>

#define BATCH 4096
#define IN_DIM 1024
#define HID 1024
#define KDIM 2048      // IN + HID
#define NGATE 4096     // 4 * HID
#define BK 64          // K-tile
#define BM 256         // M-tile
#define BN 256         // N-tile
#define NT (KDIM / BK) // 32 K-tiles
#define EPITCH2 264    // epilogue LDS pitch (shorts); 264*2=528 B, 16B-aligned

typedef __attribute__((ext_vector_type(4))) float floatx4;
typedef __attribute__((ext_vector_type(8))) __bf16 bf16x8;
typedef __attribute__((ext_vector_type(8))) unsigned short ushort8;

__device__ __forceinline__ unsigned short f2bf(float f) {
    union { float f; unsigned int u; } v; v.f = f;
    unsigned int u = v.u;
    u += 0x7fffu + ((u >> 16) & 1u);   // RNE; inputs finite
    return (unsigned short)(u >> 16);
}
__device__ __forceinline__ float bf2f(unsigned short s) {
    union { unsigned int u; float f; } v; v.u = ((unsigned int)s) << 16;
    return v.f;
}
__device__ __forceinline__ ushort8 cvt8(const float* __restrict__ src) {
    float4 v0 = ((const float4*)src)[0];
    float4 v1 = ((const float4*)src)[1];
    ushort8 o = { f2bf(v0.x), f2bf(v0.y), f2bf(v0.z), f2bf(v0.w),
                  f2bf(v1.x), f2bf(v1.y), f2bf(v1.z), f2bf(v1.w) };
    return o;
}

// ---------------------------------------------------------------------------
// prep (unchanged):
//   X  = [x | h] bf16 (4096 x 2048)
//   W  = GATE-INTERLEAVED rows: W-row (u*4+gate) = [w_gate_i[u] | w_gate_h[u]]
//   bias[u*4+gate] = b_gate_i[u] + b_gate_h[u]
// ---------------------------------------------------------------------------
__global__ __launch_bounds__(256) void prep_kernel(
    const float* __restrict__ x,  const float* __restrict__ h,
    const float* __restrict__ wii, const float* __restrict__ wih,
    const float* __restrict__ wfi, const float* __restrict__ wfh,
    const float* __restrict__ wgi, const float* __restrict__ wgh,
    const float* __restrict__ woi, const float* __restrict__ woh,
    const float* __restrict__ bii, const float* __restrict__ bih,
    const float* __restrict__ bfi, const float* __restrict__ bfh,
    const float* __restrict__ bgi, const float* __restrict__ bgh,
    const float* __restrict__ boi, const float* __restrict__ boh,
    unsigned short* __restrict__ Xb,
    unsigned short* __restrict__ Wb,
    float* __restrict__ bias)
{
    const int bid = blockIdx.x;
    const int tid = threadIdx.x;

    if (bid < 2048) {                       // x -> Xb left half
        const int e = (bid * 256 + tid) * 8;
        const int b = e >> 10, k = e & 1023;
        *(ushort8*)(Xb + (size_t)b * KDIM + k) = cvt8(x + e);
    } else if (bid < 4096) {                // h -> Xb right half
        const int e = ((bid - 2048) * 256 + tid) * 8;
        const int b = e >> 10, k = e & 1023;
        *(ushort8*)(Xb + (size_t)b * KDIM + 1024 + k) = cvt8(h + e);
    } else if (bid < 8192) {                // weights -> interleaved W rows
        const int m   = (bid - 4096) >> 9;          // 0..7, block-uniform
        const int off = (bid - 4096) & 511;
        const int e = (off * 256 + tid) * 8;
        const int n = e >> 10, k = e & 1023;
        const float* src;
        switch (m) {
            case 0: src = wii; break; case 1: src = wih; break;
            case 2: src = wfi; break; case 3: src = wfh; break;
            case 4: src = wgi; break; case 5: src = wgh; break;
            case 6: src = woi; break; default: src = woh; break;
        }
        const int gate = m >> 1, part = m & 1;
        *(ushort8*)(Wb + (size_t)(n * 4 + gate) * KDIM + part * 1024 + k)
            = cvt8(src + e);
    } else {                                // bias: 16 blocks x 256 elems
        const int t = (bid - 8192) * 256 + tid;     // 0..4095 = gate*1024+n
        const int gate = (bid - 8192) >> 2;         // block-uniform
        const int n = t & 1023;
        const float *bi, *bh_;
        switch (gate) {
            case 0: bi = bii; bh_ = bih; break;
            case 1: bi = bfi; bh_ = bfh; break;
            case 2: bi = bgi; bh_ = bgh; break;
            default: bi = boi; bh_ = boh; break;
        }
        bias[n * 4 + gate] = bi[n] + bh_[n];
    }
}

// ---------------------------------------------------------------------------
// gemm_lstm R9: 256x256 tile, BK=64, 512 threads (8 waves = 2M x 4N).
// 8-phase schedule (T3+T4+T5): 128 KiB LDS as 8 half-tile slots
// (2 dbuf x {A-lo,A-hi,B-lo,B-hi}, 16 KB each, 2 gld_lds per half).
// Counted s_waitcnt vmcnt(6) at phases 4/8 only (3 half-tiles in flight);
// raw s_barrier (asm, memory-clobbered) -- NO vmcnt(0) in the main loop.
// Keeps the proven conflict-free XOR chunk swizzle from R6.
// Fused epilogue via E[128][EPITCH2] reusing smem after the K-loop.
// ---------------------------------------------------------------------------
#define GLD16(g, l)                                                          \
    __builtin_amdgcn_global_load_lds(                                        \
        (__attribute__((address_space(1))) void*)(g),                        \
        (__attribute__((address_space(3))) void*)(l), 16, 0, 0)
#define BAR()     asm volatile("s_barrier" ::: "memory")
#define VMCNT(n)  asm volatile("s_waitcnt vmcnt(" #n ")" ::: "memory")

__global__ __launch_bounds__(512, 2) void gemm_lstm(
    const unsigned short* __restrict__ X,
    const unsigned short* __restrict__ W,
    const float* __restrict__ bias,
    const float* __restrict__ c_in,
    float* __restrict__ out)
{
    __shared__ __align__(16) unsigned char smem[131072];    // 128 KiB
    // slot layout: A[buf][half] at (buf*2+half)*16KB; B at 64KB + same
    unsigned short* sA[2][2];
    unsigned short* sB[2][2];
#pragma unroll
    for (int b_ = 0; b_ < 2; ++b_)
#pragma unroll
        for (int h_ = 0; h_ < 2; ++h_) {
            sA[b_][h_] = (unsigned short*)(smem + ((b_ * 2 + h_) << 14));
            sB[b_][h_] = (unsigned short*)(smem + 65536 + ((b_ * 2 + h_) << 14));
        }

    const int tid  = threadIdx.x;
    const int wave = tid >> 6;
    const int lane = tid & 63;
    const int idx  = lane & 15;
    const int quad = lane >> 4;
    const int wrow = wave >> 2;          // 0..1
    const int wcol = wave & 3;           // 0..3

    // XCD-aware swizzle: 256 blocks, 8 XCDs, 32 blocks each (bijective).
    const int l   = blockIdx.x;
    const int xcd = l & 7;
    const int s   = l >> 3;              // 0..31
    const int bx  = xcd * 2 + (s >> 4);  // 0..15
    const int by  = s & 15;              // 0..15
    const int rowA0 = bx * BM;
    const int rowB0 = by * BN;

    // staging: srow = tid>>3 (0..63), chunk-XOR swizzle in the global source
    const int srow = tid >> 3;
    const int skk  = ((tid & 7) ^ (srow & 7)) * 8;
    const unsigned short* gA = X + (size_t)(rowA0 + srow) * KDIM + skk;
    const unsigned short* gB = W + (size_t)(rowB0 + srow) * KDIM + skk;

#define STAGE_A(buf, ht, kt) do {                                             \
    GLD16(gA + ((size_t)((ht) * 128)) * KDIM + (size_t)(kt) * 64,             \
          sA[buf][ht] + tid * 8);                                             \
    GLD16(gA + ((size_t)((ht) * 128 + 64)) * KDIM + (size_t)(kt) * 64,        \
          sA[buf][ht] + 4096 + tid * 8);                                      \
  } while (0)
#define STAGE_B(buf, ht, kt) do {                                             \
    GLD16(gB + ((size_t)((ht) * 128)) * KDIM + (size_t)(kt) * 64,             \
          sB[buf][ht] + tid * 8);                                             \
    GLD16(gB + ((size_t)((ht) * 128 + 64)) * KDIM + (size_t)(kt) * 64,        \
          sB[buf][ht] + 4096 + tid * 8);                                      \
  } while (0)

    // fragment read addressing (row&7 == idx&7 for all read rows)
    const int aoff = (wrow * 64 + idx) * 64;
    const int boff = (wcol * 32 + idx) * 64;
    const int co0  = (quad ^ (idx & 7)) * 8;
    const int co1  = ((4 + quad) ^ (idx & 7)) * 8;

    bf16x8 af[4][2], bfr[2][2];
    floatx4 acc[2][2][4][2] = {};

#define RD_A(buf, MH) do {                                                    \
    const unsigned short* pA_ = sA[buf][MH] + aoff;                           \
    _Pragma("unroll") for (int i_ = 0; i_ < 4; ++i_) {                        \
        af[i_][0] = *(const bf16x8*)(pA_ + i_ * 1024 + co0);                  \
        af[i_][1] = *(const bf16x8*)(pA_ + i_ * 1024 + co1); }                \
  } while (0)
#define RD_B(buf, NH) do {                                                    \
    const unsigned short* pB_ = sB[buf][NH] + boff;                           \
    _Pragma("unroll") for (int j_ = 0; j_ < 2; ++j_) {                        \
        bfr[j_][0] = *(const bf16x8*)(pB_ + j_ * 1024 + co0);                 \
        bfr[j_][1] = *(const bf16x8*)(pB_ + j_ * 1024 + co1); }               \
  } while (0)
#define MM(MH, NH) do {                                                       \
    __builtin_amdgcn_s_setprio(1);                                            \
    _Pragma("unroll") for (int i_ = 0; i_ < 4; ++i_)                          \
    _Pragma("unroll") for (int j_ = 0; j_ < 2; ++j_) {                        \
        acc[MH][NH][i_][j_] = __builtin_amdgcn_mfma_f32_16x16x32_bf16(        \
            af[i_][0], bfr[j_][0], acc[MH][NH][i_][j_], 0, 0, 0);             \
        acc[MH][NH][i_][j_] = __builtin_amdgcn_mfma_f32_16x16x32_bf16(        \
            af[i_][1], bfr[j_][1], acc[MH][NH][i_][j_], 0, 0, 0); }           \
    __builtin_amdgcn_s_setprio(0);                                            \
  } while (0)

    // -------- prologue: tile0 {AL,BL,BH,AH} -> buf0; tile1 {AL,BH,AH} -> buf1
    STAGE_A(0, 0, 0); STAGE_B(0, 0, 0); STAGE_B(0, 1, 0); STAGE_A(0, 1, 0);
    STAGE_A(1, 0, 1); STAGE_B(1, 1, 1); STAGE_A(1, 1, 1);
    VMCNT(6);        // tile0 fully resident; 3 half-tiles of tile1 in flight
    BAR();

    // -------- steady-state: 15 groups of 2 K-tiles, no guards needed
    for (int t0 = 0; t0 < NT - 2; t0 += 2) {
        const int t1 = t0 + 1;
        // P1: Q1(t0)=(AL,BL)             issue BL(t1)
        RD_A(0, 0); RD_B(0, 0); STAGE_B(1, 0, t1);     BAR(); MM(0, 0); BAR();
        // P2: Q2(t0)=BH (A reused)       issue AL(t0+2)
        RD_B(0, 1);             STAGE_A(0, 0, t0 + 2); BAR(); MM(0, 1); BAR();
        // P3: Q3(t0)=AH (B reused)       issue BH(t0+2)
        RD_A(0, 1);             STAGE_B(0, 1, t0 + 2); BAR(); MM(1, 1); BAR();
        // P4: Q4(t0)=BL re-read          issue AH(t0+2); counted wait
        RD_B(0, 0);             STAGE_A(0, 1, t0 + 2); VMCNT(6);
                                                       BAR(); MM(1, 0); BAR();
        // P5: Q1(t1)                     issue BL(t0+2)
        RD_A(1, 0); RD_B(1, 0); STAGE_B(0, 0, t0 + 2); BAR(); MM(0, 0); BAR();
        // P6: Q2(t1)                     issue AL(t1+2)
        RD_B(1, 1);             STAGE_A(1, 0, t1 + 2); BAR(); MM(0, 1); BAR();
        // P7: Q3(t1)                     issue BH(t1+2)
        RD_A(1, 1);             STAGE_B(1, 1, t1 + 2); BAR(); MM(1, 1); BAR();
        // P8: Q4(t1)                     issue AH(t1+2); counted wait
        RD_B(1, 0);             STAGE_A(1, 1, t1 + 2); VMCNT(6);
                                                       BAR(); MM(1, 0); BAR();
    }
    // -------- tail group: tiles 30 (buf0), 31 (buf1); drain once
    {
        RD_A(0, 0); RD_B(0, 0); STAGE_B(1, 0, NT - 1); BAR(); MM(0, 0); BAR();
        RD_B(0, 1);                                    BAR(); MM(0, 1); BAR();
        RD_A(0, 1);                                    BAR(); MM(1, 1); BAR();
        RD_B(0, 0);             VMCNT(0);              BAR(); MM(1, 0); BAR();
        RD_A(1, 0); RD_B(1, 0);                        BAR(); MM(0, 0); BAR();
        RD_B(1, 1);                                    BAR(); MM(0, 1); BAR();
        RD_A(1, 1);                                    BAR(); MM(1, 1); BAR();
        RD_B(1, 0);                                    BAR(); MM(1, 0); BAR();
    }

    // ---- fused epilogue, two half-tile phases (rows 0-127, 128-255) ----
    unsigned short* E = (unsigned short*)smem;   // 128 x EPITCH2, 67.6 KB
    const int gate   = idx & 3;
    const int rowo16 = tid >> 4;                 // 0..31
    const int t16    = tid & 15;
    float* __restrict__ out_h = out;
    float* __restrict__ out_c = out + (size_t)BATCH * HID;

#pragma unroll
    for (int half = 0; half < 2; ++half) {
        // stage 1: every wave writes its mh==half fragments (activated)
#pragma unroll
        for (int nh = 0; nh < 2; ++nh) {
#pragma unroll
            for (int j = 0; j < 2; ++j) {
                const int col = nh * 128 + wcol * 32 + j * 16 + idx;
                const float bv = bias[rowB0 + col];
#pragma unroll
                for (int i = 0; i < 4; ++i) {
#pragma unroll
                    for (int r = 0; r < 4; ++r) {
                        const int row = wrow * 64 + i * 16 + quad * 4 + r;
                        const float v = ((half == 0) ? acc[0][nh][i][j][r]
                                                     : acc[1][nh][i][j][r]) + bv;
                        const float vv = (gate == 2) ? 2.f * v : v;
                        const float s2 = 1.f / (1.f + __expf(-vv));
                        const float a  = (gate == 2) ? 2.f * s2 - 1.f : s2;
                        E[row * EPITCH2 + col] = f2bf(a);
                    }
                }
            }
        }
        __syncthreads();

        // stage 2: all 512 threads combine 128 rows (4 passes x 32 rows)
#pragma unroll
        for (int p = 0; p < 4; ++p) {
            const int row_l = p * 32 + rowo16;
            const int row_g = rowA0 + half * 128 + row_l;
            const int colc  = t16 * 16;
            ushort8 e0 = *(const ushort8*)(E + row_l * EPITCH2 + colc);
            ushort8 e1 = *(const ushort8*)(E + row_l * EPITCH2 + colc + 8);
            const int u0 = (rowB0 >> 2) + t16 * 4;
            const float4 cv = *(const float4*)(c_in + (size_t)row_g * HID + u0);

            float cvv[4] = { cv.x, cv.y, cv.z, cv.w };
            float hp[4], cp[4];
#pragma unroll
            for (int d = 0; d < 4; ++d) {
                const ushort8& e = (d < 2) ? e0 : e1;
                const int b = (d & 1) * 4;
                const float iv = bf2f(e[b + 0]);
                const float fv = bf2f(e[b + 1]);
                const float gv = bf2f(e[b + 2]);
                const float ov = bf2f(e[b + 3]);
                const float c2 = fv * cvv[d] + iv * gv;
                const float e2 = __expf(2.f * c2);
                cp[d] = c2;
                hp[d] = ov * ((e2 - 1.f) / (e2 + 1.f));
            }
            float4 hv  = { hp[0], hp[1], hp[2], hp[3] };
            float4 cpv = { cp[0], cp[1], cp[2], cp[3] };
            *(float4*)(out_h + (size_t)row_g * HID + u0) = hv;
            *(float4*)(out_c + (size_t)row_g * HID + u0) = cpv;
        }
        __syncthreads();   // E reads done before next half's writes
    }
}

// ---------------------------------------------------------------------------
extern "C" void kernel_launch(void* const* d_in, const int* in_sizes, int n_in,
                              void* d_out, int out_size, void* d_ws, size_t ws_size,
                              hipStream_t stream) {
    const float* x   = (const float*)d_in[0];
    const float* h   = (const float*)d_in[1];
    const float* c   = (const float*)d_in[2];
    const float* wii = (const float*)d_in[3];
    const float* bii = (const float*)d_in[4];
    const float* wih = (const float*)d_in[5];
    const float* bih = (const float*)d_in[6];
    const float* wfi = (const float*)d_in[7];
    const float* bfi = (const float*)d_in[8];
    const float* wfh = (const float*)d_in[9];
    const float* bfh = (const float*)d_in[10];
    const float* wgi = (const float*)d_in[11];
    const float* bgi = (const float*)d_in[12];
    const float* wgh = (const float*)d_in[13];
    const float* bgh = (const float*)d_in[14];
    const float* woi = (const float*)d_in[15];
    const float* boi = (const float*)d_in[16];
    const float* woh = (const float*)d_in[17];
    const float* boh = (const float*)d_in[18];

    char* ws = (char*)d_ws;
    unsigned short* Xb  = (unsigned short*)ws;                        // 16 MB
    unsigned short* Wb  = (unsigned short*)(ws + ((size_t)16 << 20)); // 16 MB
    float*          bsv = (float*)(ws + ((size_t)32 << 20));          // 16 KB

    prep_kernel<<<8208, 256, 0, stream>>>(
        x, h, wii, wih, wfi, wfh, wgi, wgh, woi, woh,
        bii, bih, bfi, bfh, bgi, bgh, boi, boh, Xb, Wb, bsv);

    gemm_lstm<<<(BATCH / BM) * (NGATE / BN), 512, 0, stream>>>(
        Xb, Wb, bsv, c, (float*)d_out);
}

// Round 2
// 213.867 us; speedup vs baseline: 1.0060x; 1.0060x over previous
//
#include <hip/hip_runtime.h>
#include <stdint.h>

#define BATCH 4096
#define IN_DIM 1024
#define HID 1024
#define KDIM 2048      // IN + HID
#define NGATE 4096     // 4 * HID
#define BK 64          // K-tile
#define BM 256         // M-tile
#define BN 256         // N-tile
#define NT (KDIM / BK) // 32 K-tiles
#define EPITCH2 264    // epilogue LDS pitch (shorts); 264*2=528 B, 16B-aligned

typedef __attribute__((ext_vector_type(4))) float floatx4;
typedef __attribute__((ext_vector_type(8))) __bf16 bf16x8;
typedef __attribute__((ext_vector_type(8))) unsigned short ushort8;

__device__ __forceinline__ unsigned short f2bf(float f) {
    union { float f; unsigned int u; } v; v.f = f;
    unsigned int u = v.u;
    u += 0x7fffu + ((u >> 16) & 1u);   // RNE; inputs finite
    return (unsigned short)(u >> 16);
}
__device__ __forceinline__ float bf2f(unsigned short s) {
    union { unsigned int u; float f; } v; v.u = ((unsigned int)s) << 16;
    return v.f;
}
__device__ __forceinline__ ushort8 cvt8(const float* __restrict__ src) {
    float4 v0 = ((const float4*)src)[0];
    float4 v1 = ((const float4*)src)[1];
    ushort8 o = { f2bf(v0.x), f2bf(v0.y), f2bf(v0.z), f2bf(v0.w),
                  f2bf(v1.x), f2bf(v1.y), f2bf(v1.z), f2bf(v1.w) };
    return o;
}

// ---------------------------------------------------------------------------
// prep (unchanged):
//   X  = [x | h] bf16 (4096 x 2048)
//   W  = GATE-INTERLEAVED rows: W-row (u*4+gate) = [w_gate_i[u] | w_gate_h[u]]
//   bias[u*4+gate] = b_gate_i[u] + b_gate_h[u]
// ---------------------------------------------------------------------------
__global__ __launch_bounds__(256) void prep_kernel(
    const float* __restrict__ x,  const float* __restrict__ h,
    const float* __restrict__ wii, const float* __restrict__ wih,
    const float* __restrict__ wfi, const float* __restrict__ wfh,
    const float* __restrict__ wgi, const float* __restrict__ wgh,
    const float* __restrict__ woi, const float* __restrict__ woh,
    const float* __restrict__ bii, const float* __restrict__ bih,
    const float* __restrict__ bfi, const float* __restrict__ bfh,
    const float* __restrict__ bgi, const float* __restrict__ bgh,
    const float* __restrict__ boi, const float* __restrict__ boh,
    unsigned short* __restrict__ Xb,
    unsigned short* __restrict__ Wb,
    float* __restrict__ bias)
{
    const int bid = blockIdx.x;
    const int tid = threadIdx.x;

    if (bid < 2048) {                       // x -> Xb left half
        const int e = (bid * 256 + tid) * 8;
        const int b = e >> 10, k = e & 1023;
        *(ushort8*)(Xb + (size_t)b * KDIM + k) = cvt8(x + e);
    } else if (bid < 4096) {                // h -> Xb right half
        const int e = ((bid - 2048) * 256 + tid) * 8;
        const int b = e >> 10, k = e & 1023;
        *(ushort8*)(Xb + (size_t)b * KDIM + 1024 + k) = cvt8(h + e);
    } else if (bid < 8192) {                // weights -> interleaved W rows
        const int m   = (bid - 4096) >> 9;          // 0..7, block-uniform
        const int off = (bid - 4096) & 511;
        const int e = (off * 256 + tid) * 8;
        const int n = e >> 10, k = e & 1023;
        const float* src;
        switch (m) {
            case 0: src = wii; break; case 1: src = wih; break;
            case 2: src = wfi; break; case 3: src = wfh; break;
            case 4: src = wgi; break; case 5: src = wgh; break;
            case 6: src = woi; break; default: src = woh; break;
        }
        const int gate = m >> 1, part = m & 1;
        *(ushort8*)(Wb + (size_t)(n * 4 + gate) * KDIM + part * 1024 + k)
            = cvt8(src + e);
    } else {                                // bias: 16 blocks x 256 elems
        const int t = (bid - 8192) * 256 + tid;     // 0..4095 = gate*1024+n
        const int gate = (bid - 8192) >> 2;         // block-uniform
        const int n = t & 1023;
        const float *bi, *bh_;
        switch (gate) {
            case 0: bi = bii; bh_ = bih; break;
            case 1: bi = bfi; bh_ = bfh; break;
            case 2: bi = bgi; bh_ = bgh; break;
            default: bi = boi; bh_ = boh; break;
        }
        bias[n * 4 + gate] = bi[n] + bh_[n];
    }
}

// ---------------------------------------------------------------------------
// gemm_lstm R10: R9's 8-phase structure + PHASE PINNING (rule #18 fix).
// Each phase: {ds_read | gld_lds issue} -> s_barrier -> lgkmcnt(0) ->
// sched_barrier(0) -> setprio(1) MFMA x16 setprio(0) -> sched_barrier(0)
// -> s_barrier.  Without the sched_barrier pins hipcc hoists the
// register-only MFMAs across the asm barriers (R9: MfmaUtil 35.9%,
// neutral vs 2-barrier baseline).  Counted vmcnt(6) at phases 4/8 only.
// ---------------------------------------------------------------------------
#define GLD16(g, l)                                                          \
    __builtin_amdgcn_global_load_lds(                                        \
        (__attribute__((address_space(1))) void*)(g),                        \
        (__attribute__((address_space(3))) void*)(l), 16, 0, 0)
#define BAR()     asm volatile("s_barrier" ::: "memory")
#define VMCNT(n)  asm volatile("s_waitcnt vmcnt(" #n ")" ::: "memory")
#define WAITL0()  asm volatile("s_waitcnt lgkmcnt(0)" ::: "memory")
#define SCHED0()  __builtin_amdgcn_sched_barrier(0)

__global__ __launch_bounds__(512, 2) void gemm_lstm(
    const unsigned short* __restrict__ X,
    const unsigned short* __restrict__ W,
    const float* __restrict__ bias,
    const float* __restrict__ c_in,
    float* __restrict__ out)
{
    __shared__ __align__(16) unsigned char smem[131072];    // 128 KiB
    // slot layout: A[buf][half] at (buf*2+half)*16KB; B at 64KB + same
    unsigned short* sA[2][2];
    unsigned short* sB[2][2];
#pragma unroll
    for (int b_ = 0; b_ < 2; ++b_)
#pragma unroll
        for (int h_ = 0; h_ < 2; ++h_) {
            sA[b_][h_] = (unsigned short*)(smem + ((b_ * 2 + h_) << 14));
            sB[b_][h_] = (unsigned short*)(smem + 65536 + ((b_ * 2 + h_) << 14));
        }

    const int tid  = threadIdx.x;
    const int wave = tid >> 6;
    const int lane = tid & 63;
    const int idx  = lane & 15;
    const int quad = lane >> 4;
    const int wrow = wave >> 2;          // 0..1
    const int wcol = wave & 3;           // 0..3

    // XCD-aware swizzle: 256 blocks, 8 XCDs, 32 blocks each (bijective).
    const int l   = blockIdx.x;
    const int xcd = l & 7;
    const int s   = l >> 3;              // 0..31
    const int bx  = xcd * 2 + (s >> 4);  // 0..15
    const int by  = s & 15;              // 0..15
    const int rowA0 = bx * BM;
    const int rowB0 = by * BN;

    // staging: srow = tid>>3 (0..63), chunk-XOR swizzle in the global source
    const int srow = tid >> 3;
    const int skk  = ((tid & 7) ^ (srow & 7)) * 8;
    const unsigned short* gA = X + (size_t)(rowA0 + srow) * KDIM + skk;
    const unsigned short* gB = W + (size_t)(rowB0 + srow) * KDIM + skk;

#define STAGE_A(buf, ht, kt) do {                                             \
    GLD16(gA + ((size_t)((ht) * 128)) * KDIM + (size_t)(kt) * 64,             \
          sA[buf][ht] + tid * 8);                                             \
    GLD16(gA + ((size_t)((ht) * 128 + 64)) * KDIM + (size_t)(kt) * 64,        \
          sA[buf][ht] + 4096 + tid * 8);                                      \
  } while (0)
#define STAGE_B(buf, ht, kt) do {                                             \
    GLD16(gB + ((size_t)((ht) * 128)) * KDIM + (size_t)(kt) * 64,             \
          sB[buf][ht] + tid * 8);                                             \
    GLD16(gB + ((size_t)((ht) * 128 + 64)) * KDIM + (size_t)(kt) * 64,        \
          sB[buf][ht] + 4096 + tid * 8);                                      \
  } while (0)

    // fragment read addressing (row&7 == idx&7 for all read rows)
    const int aoff = (wrow * 64 + idx) * 64;
    const int boff = (wcol * 32 + idx) * 64;
    const int co0  = (quad ^ (idx & 7)) * 8;
    const int co1  = ((4 + quad) ^ (idx & 7)) * 8;

    bf16x8 af[4][2], bfr[2][2];
    floatx4 acc[2][2][4][2] = {};

#define RD_A(buf, MH) do {                                                    \
    const unsigned short* pA_ = sA[buf][MH] + aoff;                           \
    _Pragma("unroll") for (int i_ = 0; i_ < 4; ++i_) {                        \
        af[i_][0] = *(const bf16x8*)(pA_ + i_ * 1024 + co0);                  \
        af[i_][1] = *(const bf16x8*)(pA_ + i_ * 1024 + co1); }                \
  } while (0)
#define RD_B(buf, NH) do {                                                    \
    const unsigned short* pB_ = sB[buf][NH] + boff;                           \
    _Pragma("unroll") for (int j_ = 0; j_ < 2; ++j_) {                        \
        bfr[j_][0] = *(const bf16x8*)(pB_ + j_ * 1024 + co0);                 \
        bfr[j_][1] = *(const bf16x8*)(pB_ + j_ * 1024 + co1); }               \
  } while (0)
#define MM(MH, NH) do {                                                       \
    __builtin_amdgcn_s_setprio(1);                                            \
    _Pragma("unroll") for (int i_ = 0; i_ < 4; ++i_)                          \
    _Pragma("unroll") for (int j_ = 0; j_ < 2; ++j_) {                        \
        acc[MH][NH][i_][j_] = __builtin_amdgcn_mfma_f32_16x16x32_bf16(        \
            af[i_][0], bfr[j_][0], acc[MH][NH][i_][j_], 0, 0, 0);             \
        acc[MH][NH][i_][j_] = __builtin_amdgcn_mfma_f32_16x16x32_bf16(        \
            af[i_][1], bfr[j_][1], acc[MH][NH][i_][j_], 0, 0, 0); }           \
    __builtin_amdgcn_s_setprio(0);                                            \
  } while (0)

// pinned phase compute: barrier -> wait -> pin -> MFMA -> pin -> barrier
#define DO_MM(MH, NH) do {                                                    \
    BAR();                                                                    \
    WAITL0();                                                                 \
    SCHED0();                                                                 \
    MM(MH, NH);                                                               \
    SCHED0();                                                                 \
    BAR();                                                                    \
  } while (0)

    // -------- prologue: tile0 {AL,BL,BH,AH} -> buf0; tile1 {AL,BH,AH} -> buf1
    STAGE_A(0, 0, 0); STAGE_B(0, 0, 0); STAGE_B(0, 1, 0); STAGE_A(0, 1, 0);
    STAGE_A(1, 0, 1); STAGE_B(1, 1, 1); STAGE_A(1, 1, 1);
    VMCNT(6);        // tile0 fully resident; 3 half-tiles of tile1 in flight
    BAR();

    // -------- steady-state: 15 groups of 2 K-tiles, no guards needed
    for (int t0 = 0; t0 < NT - 2; t0 += 2) {
        const int t1 = t0 + 1;
        // P1: Q1(t0)=(AL,BL)             issue BL(t1)
        RD_A(0, 0); RD_B(0, 0); STAGE_B(1, 0, t1);     DO_MM(0, 0);
        // P2: Q2(t0)=BH (A reused)       issue AL(t0+2)
        RD_B(0, 1);             STAGE_A(0, 0, t0 + 2); DO_MM(0, 1);
        // P3: Q3(t0)=AH (B reused)       issue BH(t0+2)
        RD_A(0, 1);             STAGE_B(0, 1, t0 + 2); DO_MM(1, 1);
        // P4: Q4(t0)=BL re-read          issue AH(t0+2); counted wait
        RD_B(0, 0);             STAGE_A(0, 1, t0 + 2); VMCNT(6);
                                                       DO_MM(1, 0);
        // P5: Q1(t1)                     issue BL(t0+2)
        RD_A(1, 0); RD_B(1, 0); STAGE_B(0, 0, t0 + 2); DO_MM(0, 0);
        // P6: Q2(t1)                     issue AL(t1+2)
        RD_B(1, 1);             STAGE_A(1, 0, t1 + 2); DO_MM(0, 1);
        // P7: Q3(t1)                     issue BH(t1+2)
        RD_A(1, 1);             STAGE_B(1, 1, t1 + 2); DO_MM(1, 1);
        // P8: Q4(t1)                     issue AH(t1+2); counted wait
        RD_B(1, 0);             STAGE_A(1, 1, t1 + 2); VMCNT(6);
                                                       DO_MM(1, 0);
    }
    // -------- tail group: tiles 30 (buf0), 31 (buf1); drain once
    {
        RD_A(0, 0); RD_B(0, 0); STAGE_B(1, 0, NT - 1); DO_MM(0, 0);
        RD_B(0, 1);                                    DO_MM(0, 1);
        RD_A(0, 1);                                    DO_MM(1, 1);
        RD_B(0, 0);             VMCNT(0);              DO_MM(1, 0);
        RD_A(1, 0); RD_B(1, 0);                        DO_MM(0, 0);
        RD_B(1, 1);                                    DO_MM(0, 1);
        RD_A(1, 1);                                    DO_MM(1, 1);
        RD_B(1, 0);                                    DO_MM(1, 0);
    }

    // ---- fused epilogue, two half-tile phases (rows 0-127, 128-255) ----
    unsigned short* E = (unsigned short*)smem;   // 128 x EPITCH2, 67.6 KB
    const int gate   = idx & 3;
    const int rowo16 = tid >> 4;                 // 0..31
    const int t16    = tid & 15;
    float* __restrict__ out_h = out;
    float* __restrict__ out_c = out + (size_t)BATCH * HID;

#pragma unroll
    for (int half = 0; half < 2; ++half) {
        // stage 1: every wave writes its mh==half fragments (activated)
#pragma unroll
        for (int nh = 0; nh < 2; ++nh) {
#pragma unroll
            for (int j = 0; j < 2; ++j) {
                const int col = nh * 128 + wcol * 32 + j * 16 + idx;
                const float bv = bias[rowB0 + col];
#pragma unroll
                for (int i = 0; i < 4; ++i) {
#pragma unroll
                    for (int r = 0; r < 4; ++r) {
                        const int row = wrow * 64 + i * 16 + quad * 4 + r;
                        const float v = ((half == 0) ? acc[0][nh][i][j][r]
                                                     : acc[1][nh][i][j][r]) + bv;
                        const float vv = (gate == 2) ? 2.f * v : v;
                        const float s2 = 1.f / (1.f + __expf(-vv));
                        const float a  = (gate == 2) ? 2.f * s2 - 1.f : s2;
                        E[row * EPITCH2 + col] = f2bf(a);
                    }
                }
            }
        }
        __syncthreads();

        // stage 2: all 512 threads combine 128 rows (4 passes x 32 rows)
#pragma unroll
        for (int p = 0; p < 4; ++p) {
            const int row_l = p * 32 + rowo16;
            const int row_g = rowA0 + half * 128 + row_l;
            const int colc  = t16 * 16;
            ushort8 e0 = *(const ushort8*)(E + row_l * EPITCH2 + colc);
            ushort8 e1 = *(const ushort8*)(E + row_l * EPITCH2 + colc + 8);
            const int u0 = (rowB0 >> 2) + t16 * 4;
            const float4 cv = *(const float4*)(c_in + (size_t)row_g * HID + u0);

            float cvv[4] = { cv.x, cv.y, cv.z, cv.w };
            float hp[4], cp[4];
#pragma unroll
            for (int d = 0; d < 4; ++d) {
                const ushort8& e = (d < 2) ? e0 : e1;
                const int b = (d & 1) * 4;
                const float iv = bf2f(e[b + 0]);
                const float fv = bf2f(e[b + 1]);
                const float gv = bf2f(e[b + 2]);
                const float ov = bf2f(e[b + 3]);
                const float c2 = fv * cvv[d] + iv * gv;
                const float e2 = __expf(2.f * c2);
                cp[d] = c2;
                hp[d] = ov * ((e2 - 1.f) / (e2 + 1.f));
            }
            float4 hv  = { hp[0], hp[1], hp[2], hp[3] };
            float4 cpv = { cp[0], cp[1], cp[2], cp[3] };
            *(float4*)(out_h + (size_t)row_g * HID + u0) = hv;
            *(float4*)(out_c + (size_t)row_g * HID + u0) = cpv;
        }
        __syncthreads();   // E reads done before next half's writes
    }
}

// ---------------------------------------------------------------------------
extern "C" void kernel_launch(void* const* d_in, const int* in_sizes, int n_in,
                              void* d_out, int out_size, void* d_ws, size_t ws_size,
                              hipStream_t stream) {
    const float* x   = (const float*)d_in[0];
    const float* h   = (const float*)d_in[1];
    const float* c   = (const float*)d_in[2];
    const float* wii = (const float*)d_in[3];
    const float* bii = (const float*)d_in[4];
    const float* wih = (const float*)d_in[5];
    const float* bih = (const float*)d_in[6];
    const float* wfi = (const float*)d_in[7];
    const float* bfi = (const float*)d_in[8];
    const float* wfh = (const float*)d_in[9];
    const float* bfh = (const float*)d_in[10];
    const float* wgi = (const float*)d_in[11];
    const float* bgi = (const float*)d_in[12];
    const float* wgh = (const float*)d_in[13];
    const float* bgh = (const float*)d_in[14];
    const float* woi = (const float*)d_in[15];
    const float* boi = (const float*)d_in[16];
    const float* woh = (const float*)d_in[17];
    const float* boh = (const float*)d_in[18];

    char* ws = (char*)d_ws;
    unsigned short* Xb  = (unsigned short*)ws;                        // 16 MB
    unsigned short* Wb  = (unsigned short*)(ws + ((size_t)16 << 20)); // 16 MB
    float*          bsv = (float*)(ws + ((size_t)32 << 20));          // 16 KB

    prep_kernel<<<8208, 256, 0, stream>>>(
        x, h, wii, wih, wfi, wfh, wgi, wgh, woi, woh,
        bii, bih, bfi, bfh, bgi, bgh, boi, boh, Xb, Wb, bsv);

    gemm_lstm<<<(BATCH / BM) * (NGATE / BN), 512, 0, stream>>>(
        Xb, Wb, bsv, c, (float*)d_out);
}